// Round 16
// baseline (118.311 us; speedup 1.0000x reference)
//
#include <hip/hip_runtime.h>
#include <hip/hip_bf16.h>

typedef __bf16 bf16_8 __attribute__((ext_vector_type(8)));
typedef float f32x4 __attribute__((ext_vector_type(4)));
typedef unsigned short us4 __attribute__((ext_vector_type(4)));

#define AS1(p) ((const __attribute__((address_space(1))) void*)(p))
#define AS3(p) ((__attribute__((address_space(3))) void*)(p))

#define Bb 4
#define Tt 2048
#define Cc 768
#define NH 12
#define HD 64
#define Mrows 8192           // B*T
#define N1 2304              // 3C
#define KDIM 768
#define QSCALE 0.1803368801111204f   // 0.125 * log2(e): S comes out in log2 domain

__device__ __forceinline__ unsigned short bfbits(float x) {
    __bf16 h = (__bf16)x;
    return __builtin_bit_cast(unsigned short, h);
}

__device__ __forceinline__ float exp2fast(float x) {
#if __has_builtin(__builtin_amdgcn_exp2f)
    return __builtin_amdgcn_exp2f(x);
#else
    return __expf(0.6931471805599453f * x);
#endif
}

// ---------------- cast x (f32 -> bf16), vectorized ----------------
__global__ __launch_bounds__(256) void cast_f32_bf16(const float* __restrict__ in,
                                                     __bf16* __restrict__ out, int n4) {
    int i = blockIdx.x * blockDim.x + threadIdx.x;
    if (i < n4) {
        float4 v = ((const float4*)in)[i];
        us4 o;
        o.x = bfbits(v.x); o.y = bfbits(v.y); o.z = bfbits(v.z); o.w = bfbits(v.w);
        *(us4*)(out + (size_t)i * 4) = o;
    }
}

// ---------------- transpose-cast: in f32 [R][Cn] -> out bf16 [Cn][R] ----------------
__global__ __launch_bounds__(256) void transpose_cast(const float* __restrict__ in,
                                                      __bf16* __restrict__ out, int R, int Cn) {
    __shared__ float tile[32][33];
    int c0 = blockIdx.x * 32, r0 = blockIdx.y * 32;
    int tx = threadIdx.x, ty = threadIdx.y;
#pragma unroll
    for (int i = 0; i < 4; ++i)
        tile[ty + i * 8][tx] = in[(size_t)(r0 + ty + i * 8) * Cn + c0 + tx];
    __syncthreads();
#pragma unroll
    for (int i = 0; i < 4; ++i)
        out[(size_t)(c0 + ty + i * 8) * R + r0 + tx] = (__bf16)tile[tx][ty + i * 8];
}

// ---------------- bf16 GEMM v7: 128x192 tile for BOTH modes ----------------
// Round-15 proved 192-wide on MODE 0 (−11 µs). MODE 1 (proj, N=768) now also 192:
// grid 64x4 = 256 blocks = exactly 1/CU (perfect balance; old 128² was 384 = 1.5/CU
// -> wall = 2 sequential blocks on half the CUs). Same verified 2-barrier skeleton;
// only constexpr parameters differ. vmcnt(5) = 2 A + 3 B chunks in flight.
template <int MODE>
__global__ __launch_bounds__(256, 3) void gemm_bt(
        const __bf16* __restrict__ A,
        const __bf16* __restrict__ Bt,
        const float* __restrict__ bias,
        float* __restrict__ outf,
        __bf16* __restrict__ qb,
        __bf16* __restrict__ kb,
        __bf16* __restrict__ vTb,
        int M, int N, int K) {
    constexpr int BN  = 192;                   // tile width
    constexpr int NF  = BN / 32;               // n-frags per wave (6)
    constexpr int BCH = 3;                     // B 16B-chunks per thread per tile
    constexpr int ASZ = 128 * 32;              // elems per A buffer
    constexpr int BSZ = BN * 32;               // elems per B buffer
    constexpr int SMEMSZ = (MODE == 0) ? (128 * 192) : (2 * ASZ + 2 * BSZ);
    __shared__ __bf16 SMEM[SMEMSZ];            // staging = 2*ASZ+2*BSZ; MODE0 Cs reuse

    int tid = threadIdx.x;
    int w = tid >> 6, l = tid & 63, lr = l & 15, lg = l >> 4;
    int wm = w >> 1, wn = w & 1;

    int gx = gridDim.x, gy = gridDim.y;
    int nwg = gx * gy;
    int orig = blockIdx.y * gx + blockIdx.x;
    int q8 = nwg >> 3, r8 = nwg & 7;
    int xcd = orig & 7, rest = orig >> 3;
    int swz = (xcd < r8) ? xcd * (q8 + 1) + rest
                         : r8 * (q8 + 1) + (xcd - r8) * q8 + rest;
    int bx = swz / gy, by = swz % gy;
    int m0 = bx * 128, n0 = by * BN;

    f32x4 acc[4][NF] = {};

#define GSTAGE(buf, kk) do {                                                                 \
    _Pragma("unroll")                                                                        \
    for (int i_ = 0; i_ < 2; ++i_) {                                                         \
        int c_ = i_ * 256 + tid;                                                             \
        int row_ = c_ >> 2;                                                                  \
        int jc_ = ((c_ & 3) ^ (row_ & 3)) << 3;                                              \
        __builtin_amdgcn_global_load_lds(AS1(A + (size_t)(m0 + row_) * K + (kk) + jc_),      \
                                         AS3(&SMEM[(buf) * ASZ + c_ * 8]), 16, 0, 0);        \
    }                                                                                        \
    _Pragma("unroll")                                                                        \
    for (int i_ = 0; i_ < BCH; ++i_) {                                                       \
        int c_ = i_ * 256 + tid;                                                             \
        int row_ = c_ >> 2;                                                                  \
        int jc_ = ((c_ & 3) ^ (row_ & 3)) << 3;                                              \
        __builtin_amdgcn_global_load_lds(AS1(Bt + (size_t)(n0 + row_) * K + (kk) + jc_),     \
                                         AS3(&SMEM[2 * ASZ + (buf) * BSZ + c_ * 8]), 16, 0, 0); \
    }                                                                                        \
} while (0)

    GSTAGE(0, 0);
    asm volatile("s_waitcnt vmcnt(0)" ::: "memory");
    __builtin_amdgcn_sched_barrier(0);
    __builtin_amdgcn_s_barrier();
    __builtin_amdgcn_sched_barrier(0);

    int nkt = K >> 5;
    for (int kt = 0; kt < nkt; ++kt) {
        int cur = kt & 1;
        if (kt + 1 < nkt) {
            GSTAGE(cur ^ 1, (kt + 1) * 32);
            asm volatile("s_waitcnt vmcnt(5)" ::: "memory");   // 2 A + 3 B in flight
        } else {
            asm volatile("s_waitcnt vmcnt(0)" ::: "memory");
        }
        __builtin_amdgcn_sched_barrier(0);
        __builtin_amdgcn_s_barrier();
        __builtin_amdgcn_sched_barrier(0);

        const __bf16* Ac = &SMEM[cur * ASZ];
        const __bf16* Bc = &SMEM[2 * ASZ + cur * BSZ];
        bf16_8 af[4], bfr[NF];
#pragma unroll
        for (int mi = 0; mi < 4; ++mi)
            af[mi] = *(const bf16_8*)&Ac[(wm * 64 + mi * 16 + lr) * 32 +
                                         ((lg ^ (lr & 3)) << 3)];
#pragma unroll
        for (int ni = 0; ni < NF; ++ni)
            bfr[ni] = *(const bf16_8*)&Bc[(wn * (BN / 2) + ni * 16 + lr) * 32 +
                                          ((lg ^ (lr & 3)) << 3)];
#pragma unroll
        for (int mi = 0; mi < 4; ++mi)
#pragma unroll
            for (int ni = 0; ni < NF; ++ni)
                acc[mi][ni] = __builtin_amdgcn_mfma_f32_16x16x32_bf16(af[mi], bfr[ni],
                                                                      acc[mi][ni], 0, 0, 0);
        asm volatile("s_waitcnt lgkmcnt(0)" ::: "memory");
        __builtin_amdgcn_sched_barrier(0);
        __builtin_amdgcn_s_barrier();
        __builtin_amdgcn_sched_barrier(0);
    }

    int seg = (MODE == 0) ? (n0 / Cc) : 0;
    if (MODE == 0 && seg < 2) {
        // ---- coalesced path: C -> LDS (bf16, bias+scale applied) -> 16B stores ----
        __bf16* Cs = &SMEM[0];               // 128 x BN bf16
        float sc = (seg == 0) ? QSCALE : 1.0f;
#pragma unroll
        for (int ni = 0; ni < NF; ++ni) {
            int lnn = wn * (BN / 2) + ni * 16 + lr;
            float bv = bias[n0 + lnn];
#pragma unroll
            for (int mi = 0; mi < 4; ++mi) {
                int lm0 = wm * 64 + mi * 16 + lg * 4;
                f32x4 v = acc[mi][ni];
#pragma unroll
                for (int r = 0; r < 4; ++r)
                    Cs[(lm0 + r) * BN + lnn] = (__bf16)((v[r] + bv) * sc);
            }
        }
        // drain ds_writes before the rendezvous (raw s_barrier does not wait lgkmcnt)
        asm volatile("s_waitcnt lgkmcnt(0)" ::: "memory");
        __builtin_amdgcn_sched_barrier(0);
        __builtin_amdgcn_s_barrier();
        __builtin_amdgcn_sched_barrier(0);
        __bf16* base = seg ? kb : qb;
        int nrem = n0 - seg * Cc;
        constexpr int CPR = BN / 8;          // 16B chunks per row
        constexpr int NST = 128 * CPR / 256; // store chunks per thread
#pragma unroll
        for (int i = 0; i < NST; ++i) {
            int c = i * 256 + tid;
            int lm = c / CPR, ln8 = (c % CPR) * 8;
            int t = m0 + lm;
            int b = t >> 11, tt = t & 2047;
            int col = nrem + ln8;
            int h = col >> 6, d = col & 63;
            *(bf16_8*)(base + ((size_t)(b * NH + h) * Tt + tt) * HD + d) =
                *(const bf16_8*)&Cs[lm * BN + ln8];
        }
    } else {
#pragma unroll
        for (int ni = 0; ni < NF; ++ni) {
            int gn = n0 + wn * (BN / 2) + ni * 16 + lr;
            float bv = bias[gn];
#pragma unroll
            for (int mi = 0; mi < 4; ++mi) {
                int gm0 = m0 + wm * 64 + mi * 16 + lg * 4;
                f32x4 v = acc[mi][ni];
                if (MODE == 1) {
#pragma unroll
                    for (int r = 0; r < 4; ++r)
                        outf[(size_t)(gm0 + r) * N + gn] = v[r] + bv;
                } else {
                    int rem = gn - 2 * Cc;
                    int h = rem >> 6, d = rem & 63;
                    int b = gm0 >> 11, t = gm0 & 2047;
                    size_t bh = (size_t)b * NH + h;
                    us4 pk;
#pragma unroll
                    for (int r = 0; r < 4; ++r) pk[r] = bfbits(v[r] + bv);
                    *(us4*)(vTb + (bh * HD + d) * Tt + t) = pk;
                }
            }
        }
    }
}

// ---------------- flash attention v8 (round 8, verbatim): best-known attn ------------
__global__ __launch_bounds__(256, 2) void attn_fwd(const __bf16* __restrict__ q,
                                                   const __bf16* __restrict__ k,
                                                   const __bf16* __restrict__ vT,
                                                   __bf16* __restrict__ aout) {
    __shared__ __bf16 Ks[2][64 * 64];
    __shared__ __bf16 Vs[2][64 * 64];
    __shared__ __bf16 Ps[4][16 * 64];       // XOR-swizzled (16B units ^ row&7)
    const float NEGINF = -__builtin_inff();

    int blk = blockIdx.x;
    int bh = blk % 48;               // same bh -> same XCD (48 % 8 == 0)
    int j = blk / 48;                // 0..15
    int qtA = j, qtB = 31 - j;
    int tid = threadIdx.x;
    int w = tid >> 6, l = tid & 63, lr = l & 15, lg = l >> 4;

    const __bf16* qp = q + (size_t)bh * Tt * HD;
    const __bf16* kp = k + (size_t)bh * Tt * HD;
    const __bf16* vp = vT + (size_t)bh * HD * Tt;

    bf16_8 qfA0, qfA1, qfB0, qfB1;
    {
        int q0A = qtA * 64 + w * 16, q0B = qtB * 64 + w * 16;
        qfA0 = *(const bf16_8*)(qp + (size_t)(q0A + lr) * HD + lg * 8);
        qfA1 = *(const bf16_8*)(qp + (size_t)(q0A + lr) * HD + 32 + lg * 8);
        qfB0 = *(const bf16_8*)(qp + (size_t)(q0B + lr) * HD + lg * 8);
        qfB1 = *(const bf16_8*)(qp + (size_t)(q0B + lr) * HD + 32 + lg * 8);
    }

    f32x4 accOA[4] = {}, accOB[4] = {};
    float sA[4] = {}, sB[4] = {};

    const int swz = lr & 7;
    const int co0 = (lg ^ swz) * 8;
    const int co1 = ((4 + lg) ^ swz) * 8;
    const int qloc = w * 16 + lg * 4;     // +r : row within 64-row q-tile
    __bf16* Pw = &Ps[w][0];

#define STAGE(buf, kvbase) do {                                                              \
    int c0_ = tid, c1_ = 256 + tid;                                                          \
    int row0_ = c0_ >> 3, j0_ = (c0_ & 7) ^ (row0_ & 7);                                     \
    int row1_ = c1_ >> 3, j1_ = (c1_ & 7) ^ (row1_ & 7);                                     \
    __builtin_amdgcn_global_load_lds(AS1(kp + (size_t)((kvbase) + row0_) * HD + j0_ * 8),    \
                                     AS3(&Ks[buf][c0_ * 8]), 16, 0, 0);                      \
    __builtin_amdgcn_global_load_lds(AS1(vp + (size_t)row0_ * Tt + (kvbase) + j0_ * 8),      \
                                     AS3(&Vs[buf][c0_ * 8]), 16, 0, 0);                      \
    __builtin_amdgcn_global_load_lds(AS1(kp + (size_t)((kvbase) + row1_) * HD + j1_ * 8),    \
                                     AS3(&Ks[buf][c1_ * 8]), 16, 0, 0);                      \
    __builtin_amdgcn_global_load_lds(AS1(vp + (size_t)row1_ * Tt + (kvbase) + j1_ * 8),      \
                                     AS3(&Vs[buf][c1_ * 8]), 16, 0, 0);                      \
} while (0)

#define TILE_COMPUTE(qf0, qf1, accO, s, diag) do {                                           \
    f32x4 accS_[4] = {};                                                                     \
    __builtin_amdgcn_s_setprio(1);                                                           \
    _Pragma("unroll")                                                                        \
    for (int nt = 0; nt < 4; ++nt) {                                                         \
        int rb = (nt * 16 + lr) * 64;                                                        \
        bf16_8 kf0_ = *(const bf16_8*)(Kc_ + rb + co0);                                      \
        bf16_8 kf1_ = *(const bf16_8*)(Kc_ + rb + co1);                                      \
        accS_[nt] = __builtin_amdgcn_mfma_f32_16x16x32_bf16(qf0, kf0_, accS_[nt], 0, 0, 0);  \
        accS_[nt] = __builtin_amdgcn_mfma_f32_16x16x32_bf16(qf1, kf1_, accS_[nt], 0, 0, 0);  \
    }                                                                                        \
    __builtin_amdgcn_s_setprio(0);                                                           \
    if (diag) {                                                                              \
        _Pragma("unroll")                                                                    \
        for (int nt = 0; nt < 4; ++nt) {                                                     \
            int kloc_ = nt * 16 + lr;                                                        \
            _Pragma("unroll")                                                                \
            for (int r = 0; r < 4; ++r)                                                      \
                if (kloc_ > qloc + r) accS_[nt][r] = NEGINF;                                 \
        }                                                                                    \
    }                                                                                        \
    _Pragma("unroll")                                                                        \
    for (int r = 0; r < 4; ++r) {                                                            \
        int prow_ = lg * 4 + r;                                                              \
        _Pragma("unroll")                                                                    \
        for (int nt = 0; nt < 4; ++nt) {                                                     \
            float pv_ = exp2fast(accS_[nt][r]);                                              \
            s[r] += pv_;                                                                     \
            int col_ = nt * 16 + lr;                                                         \
            Pw[prow_ * 64 + (((col_ >> 3) ^ (prow_ & 7)) << 3) + (col_ & 7)] = (__bf16)pv_;  \
        }                                                                                    \
    }                                                                                        \
    bf16_8 pf0_ = *(const bf16_8*)&Pw[lr * 64 + ((lg ^ swz) << 3)];                          \
    bf16_8 pf1_ = *(const bf16_8*)&Pw[lr * 64 + (((4 + lg) ^ swz) << 3)];                    \
    __builtin_amdgcn_s_setprio(1);                                                           \
    _Pragma("unroll")                                                                        \
    for (int dt = 0; dt < 4; ++dt) {                                                         \
        int rb = (dt * 16 + lr) * 64;                                                        \
        bf16_8 vf0_ = *(const bf16_8*)(Vc_ + rb + co0);                                      \
        bf16_8 vf1_ = *(const bf16_8*)(Vc_ + rb + co1);                                      \
        accO[dt] = __builtin_amdgcn_mfma_f32_16x16x32_bf16(pf0_, vf0_, accO[dt], 0, 0, 0);   \
        accO[dt] = __builtin_amdgcn_mfma_f32_16x16x32_bf16(pf1_, vf1_, accO[dt], 0, 0, 0);   \
    }                                                                                        \
    __builtin_amdgcn_s_setprio(0);                                                           \
} while (0)

    STAGE(0, 0);
    asm volatile("s_waitcnt vmcnt(0)" ::: "memory");
    __builtin_amdgcn_sched_barrier(0);
    __builtin_amdgcn_s_barrier();
    __builtin_amdgcn_sched_barrier(0);

    for (int kv = 0; kv <= qtB; ++kv) {
        int cur = kv & 1;
        if (kv < qtB) {
            STAGE(cur ^ 1, (kv + 1) * 64);
            asm volatile("s_waitcnt vmcnt(4)" ::: "memory");
        } else {
            asm volatile("s_waitcnt vmcnt(0)" ::: "memory");
        }
        __builtin_amdgcn_sched_barrier(0);
        __builtin_amdgcn_s_barrier();
        __builtin_amdgcn_sched_barrier(0);

        const __bf16* Kc_ = &Ks[cur][0];
        const __bf16* Vc_ = &Vs[cur][0];
        TILE_COMPUTE(qfB0, qfB1, accOB, sB, kv == qtB);
        if (kv <= qtA)
            TILE_COMPUTE(qfA0, qfA1, accOA, sA, kv == qtA);

        asm volatile("s_waitcnt lgkmcnt(0)" ::: "memory");
        __builtin_amdgcn_sched_barrier(0);
        __builtin_amdgcn_s_barrier();
        __builtin_amdgcn_sched_barrier(0);
    }

    int b = bh / NH, h = bh - b * NH;
#define EPILOGUE(accO, s, qt) do {                                                           \
    _Pragma("unroll")                                                                        \
    for (int r = 0; r < 4; ++r) {                                                            \
        float ss_ = s[r];                                                                    \
        _Pragma("unroll")                                                                    \
        for (int off = 1; off < 16; off <<= 1)                                               \
            ss_ += __shfl_xor(ss_, off);                                                     \
        float inv_ = 1.0f / ss_;                                                             \
        size_t row_ = (size_t)(b * Tt + (qt) * 64 + w * 16 + lg * 4 + r) * Cc + h * HD;      \
        _Pragma("unroll")                                                                    \
        for (int dt = 0; dt < 4; ++dt)                                                       \
            aout[row_ + dt * 16 + lr] = (__bf16)(accO[dt][r] * inv_);                        \
    }                                                                                        \
} while (0)

    EPILOGUE(accOA, sA, qtA);
    EPILOGUE(accOB, sB, qtB);
}

// ---------------- launch ----------------
extern "C" void kernel_launch(void* const* d_in, const int* in_sizes, int n_in,
                              void* d_out, int out_size, void* d_ws, size_t ws_size,
                              hipStream_t stream) {
    const float* x      = (const float*)d_in[0];
    const float* w_attn = (const float*)d_in[1];
    const float* b_attn = (const float*)d_in[2];
    const float* w_proj = (const float*)d_in[3];
    const float* b_proj = (const float*)d_in[4];
    float* out = (float*)d_out;

    char* ws = (char*)d_ws;
    constexpr size_t SZ_XB   = (size_t)Mrows * KDIM * 2;
    constexpr size_t SZ_WAT  = (size_t)N1 * KDIM * 2;
    constexpr size_t SZ_WPT  = (size_t)Cc * Cc * 2;
    constexpr size_t SZ_HEAD = (size_t)Bb * NH * Tt * HD * 2;
    __bf16* xb  = (__bf16*)ws;
    __bf16* wat = (__bf16*)(ws + SZ_XB);
    __bf16* wpt = (__bf16*)(ws + SZ_XB + SZ_WAT);
    __bf16* qb  = (__bf16*)(ws + SZ_XB + SZ_WAT + SZ_WPT);
    __bf16* kb  = (__bf16*)(ws + SZ_XB + SZ_WAT + SZ_WPT + SZ_HEAD);
    __bf16* vTb = (__bf16*)(ws + SZ_XB + SZ_WAT + SZ_WPT + 2 * SZ_HEAD);
    __bf16* ao  = (__bf16*)(ws + SZ_XB + SZ_WAT + SZ_WPT + 3 * SZ_HEAD);

    cast_f32_bf16<<<(Mrows * KDIM / 4 + 255) / 256, 256, 0, stream>>>(x, xb, Mrows * KDIM / 4);
    transpose_cast<<<dim3(N1 / 32, KDIM / 32), dim3(32, 8), 0, stream>>>(w_attn, wat, KDIM, N1);
    transpose_cast<<<dim3(Cc / 32, Cc / 32), dim3(32, 8), 0, stream>>>(w_proj, wpt, Cc, Cc);

    gemm_bt<0><<<dim3(Mrows / 128, N1 / 192), 256, 0, stream>>>(
        xb, wat, b_attn, nullptr, qb, kb, vTb, Mrows, N1, KDIM);

    attn_fwd<<<48 * 16, 256, 0, stream>>>(qb, kb, vTb, ao);

    gemm_bt<1><<<dim3(Mrows / 128, Cc / 192), 256, 0, stream>>>(
        ao, wpt, b_proj, out, nullptr, nullptr, nullptr, Mrows, Cc, KDIM);
}

// Round 17
// 117.487 us; speedup vs baseline: 1.0070x; 1.0070x over previous
//
#include <hip/hip_runtime.h>
#include <hip/hip_bf16.h>

typedef __bf16 bf16_8 __attribute__((ext_vector_type(8)));
typedef float f32x4 __attribute__((ext_vector_type(4)));
typedef unsigned short us4 __attribute__((ext_vector_type(4)));

#define AS1(p) ((const __attribute__((address_space(1))) void*)(p))
#define AS3(p) ((__attribute__((address_space(3))) void*)(p))

#define Bb 4
#define Tt 2048
#define Cc 768
#define NH 12
#define HD 64
#define Mrows 8192           // B*T
#define N1 2304              // 3C
#define KDIM 768
#define QSCALE 0.1803368801111204f   // 0.125 * log2(e): S comes out in log2 domain

__device__ __forceinline__ unsigned short bfbits(float x) {
    __bf16 h = (__bf16)x;
    return __builtin_bit_cast(unsigned short, h);
}

__device__ __forceinline__ float exp2fast(float x) {
#if __has_builtin(__builtin_amdgcn_exp2f)
    return __builtin_amdgcn_exp2f(x);
#else
    return __expf(0.6931471805599453f * x);
#endif
}

// ---------------- cast x (f32 -> bf16), vectorized ----------------
__global__ __launch_bounds__(256) void cast_f32_bf16(const float* __restrict__ in,
                                                     __bf16* __restrict__ out, int n4) {
    int i = blockIdx.x * blockDim.x + threadIdx.x;
    if (i < n4) {
        float4 v = ((const float4*)in)[i];
        us4 o;
        o.x = bfbits(v.x); o.y = bfbits(v.y); o.z = bfbits(v.z); o.w = bfbits(v.w);
        *(us4*)(out + (size_t)i * 4) = o;
    }
}

// ---------------- transpose-cast: in f32 [R][Cn] -> out bf16 [Cn][R] ----------------
__global__ __launch_bounds__(256) void transpose_cast(const float* __restrict__ in,
                                                      __bf16* __restrict__ out, int R, int Cn) {
    __shared__ float tile[32][33];
    int c0 = blockIdx.x * 32, r0 = blockIdx.y * 32;
    int tx = threadIdx.x, ty = threadIdx.y;
#pragma unroll
    for (int i = 0; i < 4; ++i)
        tile[ty + i * 8][tx] = in[(size_t)(r0 + ty + i * 8) * Cn + c0 + tx];
    __syncthreads();
#pragma unroll
    for (int i = 0; i < 4; ++i)
        out[(size_t)(c0 + ty + i * 8) * R + r0 + tx] = (__bf16)tile[tx][ty + i * 8];
}

// ---------------- bf16 GEMM (round-15 best): BN param, 2-barrier dbuf skeleton ------
// MODE 0 (QKV): 128x192 — grid 64x12 = 768 = 3/CU exact; 24 MFMA/barrier-pair (r15: -11us).
// MODE 1 (proj): 128x128 — grid 64x6 = 384; measured best for proj (r16 A/B: 192 neutral-minus).
template <int MODE>
__global__ __launch_bounds__(256, (MODE == 0) ? 3 : 2) void gemm_bt(
        const __bf16* __restrict__ A,
        const __bf16* __restrict__ Bt,
        const float* __restrict__ bias,
        float* __restrict__ outf,
        __bf16* __restrict__ qb,
        __bf16* __restrict__ kb,
        __bf16* __restrict__ vTb,
        int M, int N, int K) {
    constexpr int BN  = (MODE == 0) ? 192 : 128;   // tile width
    constexpr int NF  = BN / 32;                   // n-frags per wave
    constexpr int BCH = (MODE == 0) ? 3 : 2;       // B 16B-chunks per thread per tile
    constexpr int ASZ = 128 * 32;                  // elems per A buffer
    constexpr int BSZ = BN * 32;                   // elems per B buffer
    constexpr int SMEMSZ = (MODE == 0) ? (128 * 192) : (2 * ASZ + 2 * BSZ);
    __shared__ __bf16 SMEM[SMEMSZ];                // staging = 2*ASZ+2*BSZ; MODE0 Cs reuse

    int tid = threadIdx.x;
    int w = tid >> 6, l = tid & 63, lr = l & 15, lg = l >> 4;
    int wm = w >> 1, wn = w & 1;

    int gx = gridDim.x, gy = gridDim.y;
    int nwg = gx * gy;
    int orig = blockIdx.y * gx + blockIdx.x;
    int q8 = nwg >> 3, r8 = nwg & 7;
    int xcd = orig & 7, rest = orig >> 3;
    int swz = (xcd < r8) ? xcd * (q8 + 1) + rest
                         : r8 * (q8 + 1) + (xcd - r8) * q8 + rest;
    int bx = swz / gy, by = swz % gy;
    int m0 = bx * 128, n0 = by * BN;

    f32x4 acc[4][NF] = {};

#define GSTAGE(buf, kk) do {                                                                 \
    _Pragma("unroll")                                                                        \
    for (int i_ = 0; i_ < 2; ++i_) {                                                         \
        int c_ = i_ * 256 + tid;                                                             \
        int row_ = c_ >> 2;                                                                  \
        int jc_ = ((c_ & 3) ^ (row_ & 3)) << 3;                                              \
        __builtin_amdgcn_global_load_lds(AS1(A + (size_t)(m0 + row_) * K + (kk) + jc_),      \
                                         AS3(&SMEM[(buf) * ASZ + c_ * 8]), 16, 0, 0);        \
    }                                                                                        \
    _Pragma("unroll")                                                                        \
    for (int i_ = 0; i_ < BCH; ++i_) {                                                       \
        int c_ = i_ * 256 + tid;                                                             \
        int row_ = c_ >> 2;                                                                  \
        int jc_ = ((c_ & 3) ^ (row_ & 3)) << 3;                                              \
        __builtin_amdgcn_global_load_lds(AS1(Bt + (size_t)(n0 + row_) * K + (kk) + jc_),     \
                                         AS3(&SMEM[2 * ASZ + (buf) * BSZ + c_ * 8]), 16, 0, 0); \
    }                                                                                        \
} while (0)

    GSTAGE(0, 0);
    asm volatile("s_waitcnt vmcnt(0)" ::: "memory");
    __builtin_amdgcn_sched_barrier(0);
    __builtin_amdgcn_s_barrier();
    __builtin_amdgcn_sched_barrier(0);

    int nkt = K >> 5;
    for (int kt = 0; kt < nkt; ++kt) {
        int cur = kt & 1;
        if (kt + 1 < nkt) {
            GSTAGE(cur ^ 1, (kt + 1) * 32);
            if constexpr (MODE == 0)
                asm volatile("s_waitcnt vmcnt(5)" ::: "memory");   // 2 A + 3 B in flight
            else
                asm volatile("s_waitcnt vmcnt(4)" ::: "memory");   // 2 A + 2 B in flight
        } else {
            asm volatile("s_waitcnt vmcnt(0)" ::: "memory");
        }
        __builtin_amdgcn_sched_barrier(0);
        __builtin_amdgcn_s_barrier();
        __builtin_amdgcn_sched_barrier(0);

        const __bf16* Ac = &SMEM[cur * ASZ];
        const __bf16* Bc = &SMEM[2 * ASZ + cur * BSZ];
        bf16_8 af[4], bfr[NF];
#pragma unroll
        for (int mi = 0; mi < 4; ++mi)
            af[mi] = *(const bf16_8*)&Ac[(wm * 64 + mi * 16 + lr) * 32 +
                                         ((lg ^ (lr & 3)) << 3)];
#pragma unroll
        for (int ni = 0; ni < NF; ++ni)
            bfr[ni] = *(const bf16_8*)&Bc[(wn * (BN / 2) + ni * 16 + lr) * 32 +
                                          ((lg ^ (lr & 3)) << 3)];
#pragma unroll
        for (int mi = 0; mi < 4; ++mi)
#pragma unroll
            for (int ni = 0; ni < NF; ++ni)
                acc[mi][ni] = __builtin_amdgcn_mfma_f32_16x16x32_bf16(af[mi], bfr[ni],
                                                                      acc[mi][ni], 0, 0, 0);
        asm volatile("s_waitcnt lgkmcnt(0)" ::: "memory");
        __builtin_amdgcn_sched_barrier(0);
        __builtin_amdgcn_s_barrier();
        __builtin_amdgcn_sched_barrier(0);
    }

    int seg = (MODE == 0) ? (n0 / Cc) : 0;
    if (MODE == 0 && seg < 2) {
        // ---- coalesced path: C -> LDS (bf16, bias+scale applied) -> 16B stores ----
        __bf16* Cs = &SMEM[0];               // 128 x BN bf16
        float sc = (seg == 0) ? QSCALE : 1.0f;
#pragma unroll
        for (int ni = 0; ni < NF; ++ni) {
            int lnn = wn * (BN / 2) + ni * 16 + lr;
            float bv = bias[n0 + lnn];
#pragma unroll
            for (int mi = 0; mi < 4; ++mi) {
                int lm0 = wm * 64 + mi * 16 + lg * 4;
                f32x4 v = acc[mi][ni];
#pragma unroll
                for (int r = 0; r < 4; ++r)
                    Cs[(lm0 + r) * BN + lnn] = (__bf16)((v[r] + bv) * sc);
            }
        }
        // drain ds_writes before the rendezvous (raw s_barrier does not wait lgkmcnt)
        asm volatile("s_waitcnt lgkmcnt(0)" ::: "memory");
        __builtin_amdgcn_sched_barrier(0);
        __builtin_amdgcn_s_barrier();
        __builtin_amdgcn_sched_barrier(0);
        __bf16* base = seg ? kb : qb;
        int nrem = n0 - seg * Cc;
        constexpr int CPR = BN / 8;          // 16B chunks per row
        constexpr int NST = 128 * CPR / 256; // store chunks per thread
#pragma unroll
        for (int i = 0; i < NST; ++i) {
            int c = i * 256 + tid;
            int lm = c / CPR, ln8 = (c % CPR) * 8;
            int t = m0 + lm;
            int b = t >> 11, tt = t & 2047;
            int col = nrem + ln8;
            int h = col >> 6, d = col & 63;
            *(bf16_8*)(base + ((size_t)(b * NH + h) * Tt + tt) * HD + d) =
                *(const bf16_8*)&Cs[lm * BN + ln8];
        }
    } else {
#pragma unroll
        for (int ni = 0; ni < NF; ++ni) {
            int gn = n0 + wn * (BN / 2) + ni * 16 + lr;
            float bv = bias[gn];
#pragma unroll
            for (int mi = 0; mi < 4; ++mi) {
                int gm0 = m0 + wm * 64 + mi * 16 + lg * 4;
                f32x4 v = acc[mi][ni];
                if (MODE == 1) {
#pragma unroll
                    for (int r = 0; r < 4; ++r)
                        outf[(size_t)(gm0 + r) * N + gn] = v[r] + bv;
                } else {
                    int rem = gn - 2 * Cc;
                    int h = rem >> 6, d = rem & 63;
                    int b = gm0 >> 11, t = gm0 & 2047;
                    size_t bh = (size_t)b * NH + h;
                    us4 pk;
#pragma unroll
                    for (int r = 0; r < 4; ++r) pk[r] = bfbits(v[r] + bv);
                    *(us4*)(vTb + (bh * HD + d) * Tt + t) = pk;
                }
            }
        }
    }
}

// ---------------- flash attention v8 (round 8, verbatim): best-known attn ------------
__global__ __launch_bounds__(256, 2) void attn_fwd(const __bf16* __restrict__ q,
                                                   const __bf16* __restrict__ k,
                                                   const __bf16* __restrict__ vT,
                                                   __bf16* __restrict__ aout) {
    __shared__ __bf16 Ks[2][64 * 64];
    __shared__ __bf16 Vs[2][64 * 64];
    __shared__ __bf16 Ps[4][16 * 64];       // XOR-swizzled (16B units ^ row&7)
    const float NEGINF = -__builtin_inff();

    int blk = blockIdx.x;
    int bh = blk % 48;               // same bh -> same XCD (48 % 8 == 0)
    int j = blk / 48;                // 0..15
    int qtA = j, qtB = 31 - j;
    int tid = threadIdx.x;
    int w = tid >> 6, l = tid & 63, lr = l & 15, lg = l >> 4;

    const __bf16* qp = q + (size_t)bh * Tt * HD;
    const __bf16* kp = k + (size_t)bh * Tt * HD;
    const __bf16* vp = vT + (size_t)bh * HD * Tt;

    bf16_8 qfA0, qfA1, qfB0, qfB1;
    {
        int q0A = qtA * 64 + w * 16, q0B = qtB * 64 + w * 16;
        qfA0 = *(const bf16_8*)(qp + (size_t)(q0A + lr) * HD + lg * 8);
        qfA1 = *(const bf16_8*)(qp + (size_t)(q0A + lr) * HD + 32 + lg * 8);
        qfB0 = *(const bf16_8*)(qp + (size_t)(q0B + lr) * HD + lg * 8);
        qfB1 = *(const bf16_8*)(qp + (size_t)(q0B + lr) * HD + 32 + lg * 8);
    }

    f32x4 accOA[4] = {}, accOB[4] = {};
    float sA[4] = {}, sB[4] = {};

    const int swz = lr & 7;
    const int co0 = (lg ^ swz) * 8;
    const int co1 = ((4 + lg) ^ swz) * 8;
    const int qloc = w * 16 + lg * 4;     // +r : row within 64-row q-tile
    __bf16* Pw = &Ps[w][0];

#define STAGE(buf, kvbase) do {                                                              \
    int c0_ = tid, c1_ = 256 + tid;                                                          \
    int row0_ = c0_ >> 3, j0_ = (c0_ & 7) ^ (row0_ & 7);                                     \
    int row1_ = c1_ >> 3, j1_ = (c1_ & 7) ^ (row1_ & 7);                                     \
    __builtin_amdgcn_global_load_lds(AS1(kp + (size_t)((kvbase) + row0_) * HD + j0_ * 8),    \
                                     AS3(&Ks[buf][c0_ * 8]), 16, 0, 0);                      \
    __builtin_amdgcn_global_load_lds(AS1(vp + (size_t)row0_ * Tt + (kvbase) + j0_ * 8),      \
                                     AS3(&Vs[buf][c0_ * 8]), 16, 0, 0);                      \
    __builtin_amdgcn_global_load_lds(AS1(kp + (size_t)((kvbase) + row1_) * HD + j1_ * 8),    \
                                     AS3(&Ks[buf][c1_ * 8]), 16, 0, 0);                      \
    __builtin_amdgcn_global_load_lds(AS1(vp + (size_t)row1_ * Tt + (kvbase) + j1_ * 8),      \
                                     AS3(&Vs[buf][c1_ * 8]), 16, 0, 0);                      \
} while (0)

#define TILE_COMPUTE(qf0, qf1, accO, s, diag) do {                                           \
    f32x4 accS_[4] = {};                                                                     \
    __builtin_amdgcn_s_setprio(1);                                                           \
    _Pragma("unroll")                                                                        \
    for (int nt = 0; nt < 4; ++nt) {                                                         \
        int rb = (nt * 16 + lr) * 64;                                                        \
        bf16_8 kf0_ = *(const bf16_8*)(Kc_ + rb + co0);                                      \
        bf16_8 kf1_ = *(const bf16_8*)(Kc_ + rb + co1);                                      \
        accS_[nt] = __builtin_amdgcn_mfma_f32_16x16x32_bf16(qf0, kf0_, accS_[nt], 0, 0, 0);  \
        accS_[nt] = __builtin_amdgcn_mfma_f32_16x16x32_bf16(qf1, kf1_, accS_[nt], 0, 0, 0);  \
    }                                                                                        \
    __builtin_amdgcn_s_setprio(0);                                                           \
    if (diag) {                                                                              \
        _Pragma("unroll")                                                                    \
        for (int nt = 0; nt < 4; ++nt) {                                                     \
            int kloc_ = nt * 16 + lr;                                                        \
            _Pragma("unroll")                                                                \
            for (int r = 0; r < 4; ++r)                                                      \
                if (kloc_ > qloc + r) accS_[nt][r] = NEGINF;                                 \
        }                                                                                    \
    }                                                                                        \
    _Pragma("unroll")                                                                        \
    for (int r = 0; r < 4; ++r) {                                                            \
        int prow_ = lg * 4 + r;                                                              \
        _Pragma("unroll")                                                                    \
        for (int nt = 0; nt < 4; ++nt) {                                                     \
            float pv_ = exp2fast(accS_[nt][r]);                                              \
            s[r] += pv_;                                                                     \
            int col_ = nt * 16 + lr;                                                         \
            Pw[prow_ * 64 + (((col_ >> 3) ^ (prow_ & 7)) << 3) + (col_ & 7)] = (__bf16)pv_;  \
        }                                                                                    \
    }                                                                                        \
    bf16_8 pf0_ = *(const bf16_8*)&Pw[lr * 64 + ((lg ^ swz) << 3)];                          \
    bf16_8 pf1_ = *(const bf16_8*)&Pw[lr * 64 + (((4 + lg) ^ swz) << 3)];                    \
    __builtin_amdgcn_s_setprio(1);                                                           \
    _Pragma("unroll")                                                                        \
    for (int dt = 0; dt < 4; ++dt) {                                                         \
        int rb = (dt * 16 + lr) * 64;                                                        \
        bf16_8 vf0_ = *(const bf16_8*)(Vc_ + rb + co0);                                      \
        bf16_8 vf1_ = *(const bf16_8*)(Vc_ + rb + co1);                                      \
        accO[dt] = __builtin_amdgcn_mfma_f32_16x16x32_bf16(pf0_, vf0_, accO[dt], 0, 0, 0);   \
        accO[dt] = __builtin_amdgcn_mfma_f32_16x16x32_bf16(pf1_, vf1_, accO[dt], 0, 0, 0);   \
    }                                                                                        \
    __builtin_amdgcn_s_setprio(0);                                                           \
} while (0)

    STAGE(0, 0);
    asm volatile("s_waitcnt vmcnt(0)" ::: "memory");
    __builtin_amdgcn_sched_barrier(0);
    __builtin_amdgcn_s_barrier();
    __builtin_amdgcn_sched_barrier(0);

    for (int kv = 0; kv <= qtB; ++kv) {
        int cur = kv & 1;
        if (kv < qtB) {
            STAGE(cur ^ 1, (kv + 1) * 64);
            asm volatile("s_waitcnt vmcnt(4)" ::: "memory");
        } else {
            asm volatile("s_waitcnt vmcnt(0)" ::: "memory");
        }
        __builtin_amdgcn_sched_barrier(0);
        __builtin_amdgcn_s_barrier();
        __builtin_amdgcn_sched_barrier(0);

        const __bf16* Kc_ = &Ks[cur][0];
        const __bf16* Vc_ = &Vs[cur][0];
        TILE_COMPUTE(qfB0, qfB1, accOB, sB, kv == qtB);
        if (kv <= qtA)
            TILE_COMPUTE(qfA0, qfA1, accOA, sA, kv == qtA);

        asm volatile("s_waitcnt lgkmcnt(0)" ::: "memory");
        __builtin_amdgcn_sched_barrier(0);
        __builtin_amdgcn_s_barrier();
        __builtin_amdgcn_sched_barrier(0);
    }

    int b = bh / NH, h = bh - b * NH;
#define EPILOGUE(accO, s, qt) do {                                                           \
    _Pragma("unroll")                                                                        \
    for (int r = 0; r < 4; ++r) {                                                            \
        float ss_ = s[r];                                                                    \
        _Pragma("unroll")                                                                    \
        for (int off = 1; off < 16; off <<= 1)                                               \
            ss_ += __shfl_xor(ss_, off);                                                     \
        float inv_ = 1.0f / ss_;                                                             \
        size_t row_ = (size_t)(b * Tt + (qt) * 64 + w * 16 + lg * 4 + r) * Cc + h * HD;      \
        _Pragma("unroll")                                                                    \
        for (int dt = 0; dt < 4; ++dt)                                                       \
            aout[row_ + dt * 16 + lr] = (__bf16)(accO[dt][r] * inv_);                        \
    }                                                                                        \
} while (0)

    EPILOGUE(accOA, sA, qtA);
    EPILOGUE(accOB, sB, qtB);
}

// ---------------- launch ----------------
extern "C" void kernel_launch(void* const* d_in, const int* in_sizes, int n_in,
                              void* d_out, int out_size, void* d_ws, size_t ws_size,
                              hipStream_t stream) {
    const float* x      = (const float*)d_in[0];
    const float* w_attn = (const float*)d_in[1];
    const float* b_attn = (const float*)d_in[2];
    const float* w_proj = (const float*)d_in[3];
    const float* b_proj = (const float*)d_in[4];
    float* out = (float*)d_out;

    char* ws = (char*)d_ws;
    constexpr size_t SZ_XB   = (size_t)Mrows * KDIM * 2;
    constexpr size_t SZ_WAT  = (size_t)N1 * KDIM * 2;
    constexpr size_t SZ_WPT  = (size_t)Cc * Cc * 2;
    constexpr size_t SZ_HEAD = (size_t)Bb * NH * Tt * HD * 2;
    __bf16* xb  = (__bf16*)ws;
    __bf16* wat = (__bf16*)(ws + SZ_XB);
    __bf16* wpt = (__bf16*)(ws + SZ_XB + SZ_WAT);
    __bf16* qb  = (__bf16*)(ws + SZ_XB + SZ_WAT + SZ_WPT);
    __bf16* kb  = (__bf16*)(ws + SZ_XB + SZ_WAT + SZ_WPT + SZ_HEAD);
    __bf16* vTb = (__bf16*)(ws + SZ_XB + SZ_WAT + SZ_WPT + 2 * SZ_HEAD);
    __bf16* ao  = (__bf16*)(ws + SZ_XB + SZ_WAT + SZ_WPT + 3 * SZ_HEAD);

    cast_f32_bf16<<<(Mrows * KDIM / 4 + 255) / 256, 256, 0, stream>>>(x, xb, Mrows * KDIM / 4);
    transpose_cast<<<dim3(N1 / 32, KDIM / 32), dim3(32, 8), 0, stream>>>(w_attn, wat, KDIM, N1);
    transpose_cast<<<dim3(Cc / 32, Cc / 32), dim3(32, 8), 0, stream>>>(w_proj, wpt, Cc, Cc);

    gemm_bt<0><<<dim3(Mrows / 128, N1 / 192), 256, 0, stream>>>(
        xb, wat, b_attn, nullptr, qb, kb, vTb, Mrows, N1, KDIM);

    attn_fwd<<<48 * 16, 256, 0, stream>>>(qb, kb, vTb, ao);

    gemm_bt<1><<<dim3(Mrows / 128, Cc / 128), 256, 0, stream>>>(
        ao, wpt, b_proj, out, nullptr, nullptr, nullptr, Mrows, Cc, KDIM);
}